// Round 14
// baseline (53.493 us; speedup 1.0000x reference)
//
#include <hip/hip_runtime.h>

// DSSIM = 1 - mean(SSIM), 11x11 gaussian (sigma=1.5), zero-pad, fp32 in/out.
// MFMA separable conv, TRANSPOSE-FREE:
//   h-blur: C[m][n] = A[m][k] x Wh[k][n]; A[m][k]=u(row m, c0+k-8), Wh[k][n]=g[k-n-3].
//   v-blur: D[m][n] = Wv[m][k] x B[k][n] where the K-index is PERMUTED by
//     sigma(jg,j) = 4jg+j (j<4) | 16+4jg+j-4 (j>=4), so that B[8jg+j][bn] is
//     exactly the lane's own h-blur C-fragment (rows 4jg+q / 16+4jg+q, col bn).
//     Wv[m=bn][k=8jg+j] = g[sigma-bn] (band; sigma-bn>10 -> 0 masks the
//     garbage tile-rows 26..31). MFMA is invariant under simultaneous
//     K-permutation of A and B, so this is exact.
// No LDS round-trip, no shuffles, no bank conflicts; occupancy VGPR-bound.

typedef _Float16 half8 __attribute__((ext_vector_type(8)));
typedef __fp16 pk16 __attribute__((ext_vector_type(2)));   // pkrtz native type
typedef float f32x4 __attribute__((ext_vector_type(4)));
typedef float f32x8 __attribute__((ext_vector_type(8)));

#define IMG_W   512
#define IMG_H   512
#define NPLANES 48
#define BR      16                  // output rows per block
#define GRX     (IMG_H / BR)        // 32
#define NBLK    (GRX * NPLANES)     // 1536

__global__ __launch_bounds__(256, 3)
void dssim_main(const float* __restrict__ xin, const float* __restrict__ yin,
                float* __restrict__ partial) {
    __shared__ float wpart[4];

    const int t    = threadIdx.x;
    const int lane = t & 63;
    const int wid  = t >> 6;
    const int bn   = lane & 15;          // fragment row/col owner
    const int jg   = lane >> 4;          // k-chunk
    const int r0   = blockIdx.x * BR;
    const bool edge = (blockIdx.x == 0) || (blockIdx.x == GRX - 1);
    const size_t pbase = (size_t)blockIdx.y * (IMG_W * IMG_H);
    const float* __restrict__ xp = xin + pbase;
    const float* __restrict__ yp = yin + pbase;

    // gaussian normalization
    float ginv;
    {
        float s = 0.f;
#pragma unroll
        for (int i = 0; i < 11; ++i) {
            float d = (float)(i - 5);
            s += expf(-(d * d) * (1.0f / 4.5f));
        }
        ginv = 1.0f / s;
    }

    // weight fragments.
    // whF (B-operand of h-MFMA): lane holds Wh[8jg+j][bn] = g[k-bn-3].
    // wvF (A-operand of v-MFMA): lane holds Wv[bn][8jg+j] = g[sigma(jg,j)-bn].
    half8 whF, wvF;
#pragma unroll
    for (int j = 0; j < 8; ++j) {
        const int k = 8 * jg + j;
        const int dh = k - bn - 3;
        const int sigma = (j < 4) ? (4 * jg + j) : (12 + 4 * jg + j);
        const int dv = sigma - bn;
        float wh = 0.f, wv = 0.f;
        if (dh >= 0 && dh < 11) {
            const float d = (float)(dh - 5);
            wh = ginv * expf(-(d * d) * (1.0f / 4.5f));
        }
        if (dv >= 0 && dv < 11) {
            const float d = (float)(dv - 5);
            wv = ginv * expf(-(d * d) * (1.0f / 4.5f));
        }
        whF[j] = (_Float16)wh;
        wvF[j] = (_Float16)wv;
    }

    // row addressing: rt0 raw rows r0-5+bn, rt1 raw rows r0+11+bn
    const int gr0 = r0 - 5 + bn;
    const bool rowok0 = (gr0 >= 0) && (gr0 < IMG_H);
    const int gr1 = r0 + 11 + bn;
    const bool rowok1 = (bn < 10) && (gr1 < IMG_H);
    const size_t row0 = (size_t)(rowok0 ? gr0 : 0) * IMG_W;
    const size_t row1 = (size_t)(rowok1 ? gr1 : 0) * IMG_W;

    // base pointers: col-tile m covers cols (wid+4m)*16 + 8jg-8 .. +8jg-1
    const int cb = (wid << 4) + (jg << 3) - 8;
    const float* bx0 = xp + row0 + cb;
    const float* by0 = yp + row0 + cb;
    const float* bx1 = xp + row1 + cb;
    const float* by1 = yp + row1 + cb;

    const f32x8 z8 = {0.f, 0.f, 0.f, 0.f, 0.f, 0.f, 0.f, 0.f};
    const f32x4 zf = {0.f, 0.f, 0.f, 0.f};
    const float C1 = 0.0001f, C2 = 0.0009f;
    float lsum = 0.f;

    f32x8 xs0, ys0, xs1, ys1;          // staged raw rows (named, static)
    half8 bU, bW, bP, bQ;              // v-MFMA B-fragments (in-register)

    // load col-tile m (compile-time m via full unroll)
#define LOADP(m)                                                            \
    {                                                                       \
        int fix = 0;                                                        \
        if ((m) == 0) fix = (wid == 0 && jg == 0) ? 8 : 0;                  \
        if ((m) == 7) fix = (wid == 3 && jg == 3) ? -8 : 0;                 \
        const int off = 64 * (m);                                           \
        xs0 = *(const f32x8*)(bx0 + off + fix);                             \
        ys0 = *(const f32x8*)(by0 + off + fix);                             \
        xs1 = *(const f32x8*)(bx1 + off + fix);                             \
        ys1 = *(const f32x8*)(by1 + off + fix);                             \
        if ((m) == 0) {                                                     \
            if (wid == 0 && jg == 0) { xs0 = z8; ys0 = z8; xs1 = z8; ys1 = z8; } \
        }                                                                   \
        if ((m) == 7) {                                                     \
            if (wid == 3 && jg == 3) { xs0 = z8; ys0 = z8; xs1 = z8; ys1 = z8; } \
        }                                                                   \
        if (edge) {                                                         \
            if (!rowok0) { xs0 = z8; ys0 = z8; }                            \
            if (!rowok1) { xs1 = z8; ys1 = z8; }                            \
        }                                                                   \
    }

    // h-blur both row-tiles from xs/ys; build v B-fragments in registers
#define HCOMP()                                                             \
    {                                                                       \
        half8 aU0, aW0, aU1, aW1;                                           \
        _Pragma("unroll")                                                   \
        for (int d = 0; d < 4; ++d) {                                       \
            const pk16 pu0 = __builtin_amdgcn_cvt_pkrtz(                    \
                xs0[2 * d] + ys0[2 * d], xs0[2 * d + 1] + ys0[2 * d + 1]);  \
            const pk16 pw0 = __builtin_amdgcn_cvt_pkrtz(                    \
                xs0[2 * d] - ys0[2 * d], xs0[2 * d + 1] - ys0[2 * d + 1]);  \
            const pk16 pu1 = __builtin_amdgcn_cvt_pkrtz(                    \
                xs1[2 * d] + ys1[2 * d], xs1[2 * d + 1] + ys1[2 * d + 1]);  \
            const pk16 pw1 = __builtin_amdgcn_cvt_pkrtz(                    \
                xs1[2 * d] - ys1[2 * d], xs1[2 * d + 1] - ys1[2 * d + 1]);  \
            aU0[2 * d] = (_Float16)pu0[0]; aU0[2 * d + 1] = (_Float16)pu0[1]; \
            aW0[2 * d] = (_Float16)pw0[0]; aW0[2 * d + 1] = (_Float16)pw0[1]; \
            aU1[2 * d] = (_Float16)pu1[0]; aU1[2 * d + 1] = (_Float16)pu1[1]; \
            aW1[2 * d] = (_Float16)pw1[0]; aW1[2 * d + 1] = (_Float16)pw1[1]; \
        }                                                                   \
        const half8 aP0 = aU0 * aU0;                                        \
        const half8 aQ0 = aW0 * aW0;                                        \
        const half8 aP1 = aU1 * aU1;                                        \
        const half8 aQ1 = aW1 * aW1;                                        \
        const f32x4 cU0 = __builtin_amdgcn_mfma_f32_16x16x32_f16(aU0, whF, zf, 0, 0, 0); \
        const f32x4 cW0 = __builtin_amdgcn_mfma_f32_16x16x32_f16(aW0, whF, zf, 0, 0, 0); \
        const f32x4 cP0 = __builtin_amdgcn_mfma_f32_16x16x32_f16(aP0, whF, zf, 0, 0, 0); \
        const f32x4 cQ0 = __builtin_amdgcn_mfma_f32_16x16x32_f16(aQ0, whF, zf, 0, 0, 0); \
        const f32x4 cU1 = __builtin_amdgcn_mfma_f32_16x16x32_f16(aU1, whF, zf, 0, 0, 0); \
        const f32x4 cW1 = __builtin_amdgcn_mfma_f32_16x16x32_f16(aW1, whF, zf, 0, 0, 0); \
        const f32x4 cP1 = __builtin_amdgcn_mfma_f32_16x16x32_f16(aP1, whF, zf, 0, 0, 0); \
        const f32x4 cQ1 = __builtin_amdgcn_mfma_f32_16x16x32_f16(aQ1, whF, zf, 0, 0, 0); \
        _Pragma("unroll")                                                   \
        for (int q = 0; q < 2; ++q) {                                       \
            const pk16 u0 = __builtin_amdgcn_cvt_pkrtz(cU0[2*q], cU0[2*q+1]); \
            const pk16 w0 = __builtin_amdgcn_cvt_pkrtz(cW0[2*q], cW0[2*q+1]); \
            const pk16 p0 = __builtin_amdgcn_cvt_pkrtz(cP0[2*q], cP0[2*q+1]); \
            const pk16 q0 = __builtin_amdgcn_cvt_pkrtz(cQ0[2*q], cQ0[2*q+1]); \
            const pk16 u1 = __builtin_amdgcn_cvt_pkrtz(cU1[2*q], cU1[2*q+1]); \
            const pk16 w1 = __builtin_amdgcn_cvt_pkrtz(cW1[2*q], cW1[2*q+1]); \
            const pk16 p1 = __builtin_amdgcn_cvt_pkrtz(cP1[2*q], cP1[2*q+1]); \
            const pk16 q1 = __builtin_amdgcn_cvt_pkrtz(cQ1[2*q], cQ1[2*q+1]); \
            bU[2*q]     = (_Float16)u0[0]; bU[2*q + 1]     = (_Float16)u0[1]; \
            bW[2*q]     = (_Float16)w0[0]; bW[2*q + 1]     = (_Float16)w0[1]; \
            bP[2*q]     = (_Float16)p0[0]; bP[2*q + 1]     = (_Float16)p0[1]; \
            bQ[2*q]     = (_Float16)q0[0]; bQ[2*q + 1]     = (_Float16)q0[1]; \
            bU[2*q + 4] = (_Float16)u1[0]; bU[2*q + 5]     = (_Float16)u1[1]; \
            bW[2*q + 4] = (_Float16)w1[0]; bW[2*q + 5]     = (_Float16)w1[1]; \
            bP[2*q + 4] = (_Float16)p1[0]; bP[2*q + 5]     = (_Float16)p1[1]; \
            bQ[2*q + 4] = (_Float16)q1[0]; bQ[2*q + 5]     = (_Float16)q1[1]; \
        }                                                                   \
    }

    // v-blur from in-register B-fragments + ssim epilogue
#define VBLUR()                                                             \
    {                                                                       \
        const f32x4 accU = __builtin_amdgcn_mfma_f32_16x16x32_f16(wvF, bU, zf, 0, 0, 0); \
        const f32x4 accW = __builtin_amdgcn_mfma_f32_16x16x32_f16(wvF, bW, zf, 0, 0, 0); \
        const f32x4 accP = __builtin_amdgcn_mfma_f32_16x16x32_f16(wvF, bP, zf, 0, 0, 0); \
        const f32x4 accQ = __builtin_amdgcn_mfma_f32_16x16x32_f16(wvF, bQ, zf, 0, 0, 0); \
        _Pragma("unroll")                                                   \
        for (int q = 0; q < 4; ++q) {                                       \
            const float U = accU[q], W = accW[q];                           \
            const float P = accP[q], Q = accQ[q];                           \
            const float U2 = U * U, W2 = W * W;                             \
            const float A = 0.5f * (U2 + W2);                               \
            const float B = 0.5f * (U2 - W2);                               \
            const float den2 = fmaf(0.5f, P + Q, -A) + C2;                  \
            const float num2 = fmaf(0.5f, P - Q, -B) + C2;                  \
            lsum += (B + C1) * num2 * __builtin_amdgcn_rcpf((A + C1) * den2); \
        }                                                                   \
    }

    // pipeline: LOAD(i+1) issued before VBLUR(i); HCOMP(i+1) after
    LOADP(0);
    HCOMP();
#pragma unroll
    for (int i = 0; i < 8; ++i) {
        if (i < 7) LOADP(i + 1);
        VBLUR();
        if (i < 7) HCOMP();
    }

    // ---- block reduction ----
#pragma unroll
    for (int off = 32; off >= 1; off >>= 1)
        lsum += __shfl_down(lsum, off, 64);
    if (lane == 0) wpart[wid] = lsum;
    __syncthreads();
    if (t == 0) {
        partial[(size_t)blockIdx.y * GRX + blockIdx.x] =
            wpart[0] + wpart[1] + wpart[2] + wpart[3];
    }
}

__global__ __launch_bounds__(256)
void dssim_final(const float* __restrict__ partial, float* __restrict__ out) {
    __shared__ double wsum[4];
    double s = 0.0;
    for (int i = threadIdx.x; i < NBLK; i += 256) s += (double)partial[i];
#pragma unroll
    for (int off = 32; off >= 1; off >>= 1)
        s += __shfl_down(s, off, 64);
    if ((threadIdx.x & 63) == 0) wsum[threadIdx.x >> 6] = s;
    __syncthreads();
    if (threadIdx.x == 0) {
        const double tot = wsum[0] + wsum[1] + wsum[2] + wsum[3];
        out[0] = (float)(1.0 - tot / 12582912.0);
    }
}

extern "C" void kernel_launch(void* const* d_in, const int* in_sizes, int n_in,
                              void* d_out, int out_size, void* d_ws, size_t ws_size,
                              hipStream_t stream) {
    const float* x = (const float*)d_in[0];
    const float* y = (const float*)d_in[1];
    float* out = (float*)d_out;
    float* partial = (float*)d_ws;   // NBLK*4 = 6 KiB

    dim3 grid(GRX, NPLANES);         // 32 x 48 = 1536 blocks
    dim3 block(256);
    dssim_main<<<grid, block, 0, stream>>>(x, y, partial);
    dssim_final<<<1, block, 0, stream>>>(partial, out);
}